// Round 1
// baseline (231.551 us; speedup 1.0000x reference)
//
#include <hip/hip_runtime.h>
#include <hip/hip_bf16.h>

// EdgeEmbedder fused kernel for MI355X (gfx950).
// Strategy:
//   precompute: p_i (512x64, bf16), relpos table (1023x64, bf16 — depends only
//               on i-j), W1/W2 bf16 casts.
//   main: per block = 64 pairs (one i, 64 consecutive j). Build all_edge tile
//         (64x256 bf16) in LDS, 2x MFMA bf16 GEMM (split-N across 4 waves),
//         fp32 bias epilogue. Output (262144,128) fp32.

typedef __attribute__((ext_vector_type(8))) short v8s;   // 8 x bf16 fragment
typedef __attribute__((ext_vector_type(4))) float v4f;   // 4 x f32 accumulator

#define PI_F 3.14159265358979323846f

// ---------------------------------------------------------------------------
// Precompute kernel: blocks 0..511 -> p rows; 512..1534 -> relpos rows;
// 1535..1630 -> W1/W2 bf16 conversion.
// ---------------------------------------------------------------------------
__global__ __launch_bounds__(64) void precompute_kernel(
    const float* __restrict__ s, const float* __restrict__ W_sp,
    const float* __restrict__ b_sp, const float* __restrict__ W_rp,
    const float* __restrict__ b_rp, const float* __restrict__ W1,
    const float* __restrict__ W2,
    __hip_bfloat16* __restrict__ p_bf, __hip_bfloat16* __restrict__ relT,
    __hip_bfloat16* __restrict__ W1b, __hip_bfloat16* __restrict__ W2b)
{
    const int b = blockIdx.x;
    const int tid = threadIdx.x;

    if (b < 512) {
        // p_i row b: p[b][f] = sum_d s[b][d] * W_sp[f][d] + b_sp[f]
        __shared__ float srow[256];
        #pragma unroll
        for (int k = 0; k < 4; k++) srow[k * 64 + tid] = s[b * 256 + k * 64 + tid];
        __syncthreads();
        float acc = b_sp[tid];
        const float* w = W_sp + tid * 256;
        #pragma unroll 8
        for (int d = 0; d < 256; d++) acc += srow[d] * w[d];
        p_bf[b * 64 + tid] = __float2bfloat16(acc);
    } else if (b < 1535) {
        // relpos row for delta index didx (rel = didx - 511)
        const int didx = b - 512;
        const float rel = (float)(didx - 511);
        __shared__ float femb[64];
        const int K = tid & 31;
        const float freq = powf(2056.0f, (2.0f * (float)K) / 64.0f);
        const float ang = rel * PI_F / freq;
        femb[tid] = (tid < 32) ? sinf(ang) : cosf(ang);
        __syncthreads();
        float acc = b_rp[tid];
        const float* w = W_rp + tid * 64;
        #pragma unroll
        for (int f = 0; f < 64; f++) acc += femb[f] * w[f];
        relT[didx * 64 + tid] = __float2bfloat16(acc);
    } else {
        // W1 (32768) then W2 (16384) fp32 -> bf16
        const int base = (b - 1535) * 512 + tid;
        #pragma unroll
        for (int k = 0; k < 8; k++) {
            int e = base + k * 64;
            if (e < 32768) W1b[e] = __float2bfloat16(W1[e]);
            else           W2b[e - 32768] = __float2bfloat16(W2[e - 32768]);
        }
    }
}

// ---------------------------------------------------------------------------
// Main fused kernel. Block = 64 pairs (rows), 256 threads (4 waves).
// Wave w computes ALL 64 rows x output cols [32w, 32w+32) -> W1/W2 read once
// per block per wave-slice (max weight reuse from L2/L1).
// ---------------------------------------------------------------------------
__global__ __launch_bounds__(256, 3) void edge_main(
    const float* __restrict__ t3, const float* __restrict__ sc3,
    const float* __restrict__ pre,
    const float* __restrict__ b1, const float* __restrict__ b2,
    const __hip_bfloat16* __restrict__ p_bf, const __hip_bfloat16* __restrict__ relT,
    const __hip_bfloat16* __restrict__ W1b, const __hip_bfloat16* __restrict__ W2b,
    float* __restrict__ out)
{
    __shared__ __hip_bfloat16 Ash[64][264];   // 256 cols + 8 pad (bank shift)
    __shared__ __hip_bfloat16 Hsh[64][136];   // 128 cols + 8 pad
    __shared__ float dtv[64];
    __shared__ float dsv[64];

    const int tid = threadIdx.x;
    const int blk = blockIdx.x;
    const int i  = blk >> 3;          // 8 blocks per i (512/64)
    const int j0 = (blk & 7) << 6;    // 64 consecutive j

    // ---- pair distances (t and sc_t) ----
    if (tid < 128) {
        const int r = tid & 63;
        const float* base = (tid < 64) ? t3 : sc3;
        const float dx = base[i * 3 + 0] - base[(j0 + r) * 3 + 0];
        const float dy = base[i * 3 + 1] - base[(j0 + r) * 3 + 1];
        const float dz = base[i * 3 + 2] - base[(j0 + r) * 3 + 2];
        const float d = sqrtf(dx * dx + dy * dy + dz * dz);
        if (tid < 64) dtv[r] = d; else dsv[r] = d;
    }

    // ---- segments A (p_i), B (p_j), C (relpos): 16B bf16 chunk copies ----
    for (int c = tid; c < 64 * 8; c += 256) {           // 2 iters
        const int r = c >> 3;
        const int cc = (c & 7) << 3;
        *(uint4*)&Ash[r][cc]       = *(const uint4*)&p_bf[i * 64 + cc];
        *(uint4*)&Ash[r][64 + cc]  = *(const uint4*)&p_bf[(j0 + r) * 64 + cc];
        *(uint4*)&Ash[r][128 + cc] = *(const uint4*)&relT[(i - (j0 + r) + 511) * 64 + cc];
    }
    // ---- segment E: pair_repr_pre (20 fp32 per row) ----
    for (int c = tid; c < 64 * 5; c += 256) {           // 2 iters
        const int r = c / 5;
        const int f4 = (c % 5) * 4;
        const float4 v = *(const float4*)&pre[(i * 512 + j0 + r) * 20 + f4];
        Ash[r][236 + f4 + 0] = __float2bfloat16(v.x);
        Ash[r][236 + f4 + 1] = __float2bfloat16(v.y);
        Ash[r][236 + f4 + 2] = __float2bfloat16(v.z);
        Ash[r][236 + f4 + 3] = __float2bfloat16(v.w);
    }
    __syncthreads();
    // ---- segment D: RBF features (needs dtv/dsv) ----
    for (int c = tid; c < 64 * 44; c += 256) {          // 11 iters
        const int r = c / 44;
        const int f = c % 44;
        const float d = (f < 22) ? dtv[r] : dsv[r];
        const int m = (f < 22) ? f : f - 22;
        const float x = (d - (float)m * (20.0f / 21.0f)) * 1.1f;  // /sigma, sigma=20/22
        Ash[r][192 + f] = __float2bfloat16(__expf(-x * x));
    }
    __syncthreads();

    // ---- MFMA phase ----
    const int wv   = tid >> 6;       // wave 0..3
    const int lane = tid & 63;
    const int l16  = lane & 15;
    const int quad = lane >> 4;
    const int nbase = wv * 32;

    float b1v0 = b1[nbase + l16],      b1v1 = b1[nbase + 16 + l16];
    float b2v0 = b2[nbase + l16],      b2v1 = b2[nbase + 16 + l16];

    // Layer 1: (64x256) @ W1^T(256x128) -> h(64x128), this wave: cols nbase..+32
    v4f acc[4][2];
    #pragma unroll
    for (int s4 = 0; s4 < 4; s4++)
        #pragma unroll
        for (int n = 0; n < 2; n++) acc[s4][n] = (v4f){0.f, 0.f, 0.f, 0.f};

    const __hip_bfloat16* w1r0 = W1b + (nbase + l16) * 256 + quad * 8;
    const __hip_bfloat16* w1r1 = w1r0 + 16 * 256;

    #pragma unroll
    for (int kt = 0; kt < 8; kt++) {
        const int ko = kt * 32 + quad * 8;
        v8s a0 = *(const v8s*)&Ash[ 0 + l16][ko];
        v8s a1 = *(const v8s*)&Ash[16 + l16][ko];
        v8s a2 = *(const v8s*)&Ash[32 + l16][ko];
        v8s a3 = *(const v8s*)&Ash[48 + l16][ko];
        v8s bb0 = *(const v8s*)(w1r0 + kt * 32);
        v8s bb1 = *(const v8s*)(w1r1 + kt * 32);
        acc[0][0] = __builtin_amdgcn_mfma_f32_16x16x32_bf16(a0, bb0, acc[0][0], 0, 0, 0);
        acc[1][0] = __builtin_amdgcn_mfma_f32_16x16x32_bf16(a1, bb0, acc[1][0], 0, 0, 0);
        acc[2][0] = __builtin_amdgcn_mfma_f32_16x16x32_bf16(a2, bb0, acc[2][0], 0, 0, 0);
        acc[3][0] = __builtin_amdgcn_mfma_f32_16x16x32_bf16(a3, bb0, acc[3][0], 0, 0, 0);
        acc[0][1] = __builtin_amdgcn_mfma_f32_16x16x32_bf16(a0, bb1, acc[0][1], 0, 0, 0);
        acc[1][1] = __builtin_amdgcn_mfma_f32_16x16x32_bf16(a1, bb1, acc[1][1], 0, 0, 0);
        acc[2][1] = __builtin_amdgcn_mfma_f32_16x16x32_bf16(a2, bb1, acc[2][1], 0, 0, 0);
        acc[3][1] = __builtin_amdgcn_mfma_f32_16x16x32_bf16(a3, bb1, acc[3][1], 0, 0, 0);
    }

    // bias + ReLU, write h to LDS in row-major (A-operand friendly) layout
    #pragma unroll
    for (int s4 = 0; s4 < 4; s4++) {
        #pragma unroll
        for (int n = 0; n < 2; n++) {
            const float bv = n ? b1v1 : b1v0;
            #pragma unroll
            for (int r = 0; r < 4; r++) {
                float v = acc[s4][n][r] + bv;
                v = fmaxf(v, 0.0f);
                Hsh[s4 * 16 + quad * 4 + r][nbase + n * 16 + l16] = __float2bfloat16(v);
            }
        }
    }
    __syncthreads();

    // Layer 2: h(64x128) @ W2^T(128x128), this wave: cols nbase..+32
    v4f acc2[4][2];
    #pragma unroll
    for (int s4 = 0; s4 < 4; s4++)
        #pragma unroll
        for (int n = 0; n < 2; n++) acc2[s4][n] = (v4f){0.f, 0.f, 0.f, 0.f};

    const __hip_bfloat16* w2r0 = W2b + (nbase + l16) * 128 + quad * 8;
    const __hip_bfloat16* w2r1 = w2r0 + 16 * 128;

    #pragma unroll
    for (int kt = 0; kt < 4; kt++) {
        const int ko = kt * 32 + quad * 8;
        v8s a0 = *(const v8s*)&Hsh[ 0 + l16][ko];
        v8s a1 = *(const v8s*)&Hsh[16 + l16][ko];
        v8s a2 = *(const v8s*)&Hsh[32 + l16][ko];
        v8s a3 = *(const v8s*)&Hsh[48 + l16][ko];
        v8s bb0 = *(const v8s*)(w2r0 + kt * 32);
        v8s bb1 = *(const v8s*)(w2r1 + kt * 32);
        acc2[0][0] = __builtin_amdgcn_mfma_f32_16x16x32_bf16(a0, bb0, acc2[0][0], 0, 0, 0);
        acc2[1][0] = __builtin_amdgcn_mfma_f32_16x16x32_bf16(a1, bb0, acc2[1][0], 0, 0, 0);
        acc2[2][0] = __builtin_amdgcn_mfma_f32_16x16x32_bf16(a2, bb0, acc2[2][0], 0, 0, 0);
        acc2[3][0] = __builtin_amdgcn_mfma_f32_16x16x32_bf16(a3, bb0, acc2[3][0], 0, 0, 0);
        acc2[0][1] = __builtin_amdgcn_mfma_f32_16x16x32_bf16(a0, bb1, acc2[0][1], 0, 0, 0);
        acc2[1][1] = __builtin_amdgcn_mfma_f32_16x16x32_bf16(a1, bb1, acc2[1][1], 0, 0, 0);
        acc2[2][1] = __builtin_amdgcn_mfma_f32_16x16x32_bf16(a2, bb1, acc2[2][1], 0, 0, 0);
        acc2[3][1] = __builtin_amdgcn_mfma_f32_16x16x32_bf16(a3, bb1, acc2[3][1], 0, 0, 0);
    }

    // epilogue: + b2, fp32 store
    const int rowbase = blk * 64;
    #pragma unroll
    for (int s4 = 0; s4 < 4; s4++) {
        #pragma unroll
        for (int n = 0; n < 2; n++) {
            const float bv = n ? b2v1 : b2v0;
            const int col = nbase + n * 16 + l16;
            #pragma unroll
            for (int r = 0; r < 4; r++) {
                const int row = rowbase + s4 * 16 + quad * 4 + r;
                out[row * 128 + col] = acc2[s4][n][r] + bv;
            }
        }
    }
}

// ---------------------------------------------------------------------------
extern "C" void kernel_launch(void* const* d_in, const int* in_sizes, int n_in,
                              void* d_out, int out_size, void* d_ws, size_t ws_size,
                              hipStream_t stream) {
    const float* s    = (const float*)d_in[0];
    const float* t3   = (const float*)d_in[1];
    const float* sc3  = (const float*)d_in[2];
    const float* pre  = (const float*)d_in[3];
    // d_in[4] = p_mask (unused by reference math: mask is all-ones and never applied)
    const float* W_sp = (const float*)d_in[5];
    const float* b_sp = (const float*)d_in[6];
    const float* W_rp = (const float*)d_in[7];
    const float* b_rp = (const float*)d_in[8];
    const float* W1   = (const float*)d_in[9];
    const float* b1   = (const float*)d_in[10];
    const float* W2   = (const float*)d_in[11];
    const float* b2   = (const float*)d_in[12];
    float* out = (float*)d_out;

    char* ws = (char*)d_ws;
    __hip_bfloat16* p_bf = (__hip_bfloat16*)(ws);                       // 64 KiB
    __hip_bfloat16* relT = (__hip_bfloat16*)(ws + 65536);               // 128 KiB (1023 rows used)
    __hip_bfloat16* W1b  = (__hip_bfloat16*)(ws + 65536 + 131072);      // 64 KiB
    __hip_bfloat16* W2b  = (__hip_bfloat16*)(ws + 65536 + 131072 + 65536); // 32 KiB

    precompute_kernel<<<1631, 64, 0, stream>>>(s, W_sp, b_sp, W_rp, b_rp, W1, W2,
                                               p_bf, relT, W1b, W2b);
    edge_main<<<4096, 256, 0, stream>>>(t3, sc3, pre, b1, b2,
                                        p_bf, relT, W1b, W2b, out);
}

// Round 2
// 219.265 us; speedup vs baseline: 1.0560x; 1.0560x over previous
//
#include <hip/hip_runtime.h>
#include <hip/hip_bf16.h>

// EdgeEmbedder fused kernel for MI355X (gfx950). Round 2.
//   R1 post-mortem: edge_main 85.5us, occupancy 27.7% (LDS 51.7KB -> 3 blk/CU),
//   MfmaUtil 11.5%, HBM 21% -> latency-bound. This round: LDS overlay union
//   (34KB -> 4 blk/CU), cheaper RBF build (no div/mod, no dist barrier),
//   preloaded kt0 weight frags, fp32-transpose epilogue for float4 stores,
//   coalesced precompute.

typedef __attribute__((ext_vector_type(8))) short v8s;   // 8 x bf16 fragment
typedef __attribute__((ext_vector_type(4))) float v4f;   // 4 x f32 accumulator

#define PI_F 3.14159265358979323846f

// ---------------------------------------------------------------------------
// Precompute: blocks 0..63 -> p rows (8/block, LDS-transposed W_sp);
// blocks 64..319 -> relpos rows (4/block, LDS-transposed W_rp);
// blocks 320..343 -> W1/W2 bf16 cast.
// ---------------------------------------------------------------------------
__global__ __launch_bounds__(256) void precompute_kernel(
    const float* __restrict__ s, const float* __restrict__ W_sp,
    const float* __restrict__ b_sp, const float* __restrict__ W_rp,
    const float* __restrict__ b_rp, const float* __restrict__ W1,
    const float* __restrict__ W2,
    __hip_bfloat16* __restrict__ p_bf, __hip_bfloat16* __restrict__ relT,
    __hip_bfloat16* __restrict__ W1b, __hip_bfloat16* __restrict__ W2b)
{
    const int b = blockIdx.x;
    const int tid = threadIdx.x;
    __shared__ float lds[128 * 65 + 8 * 256];   // 41.5 KB

    if (b < 64) {
        // p rows row0..row0+7: p[r][f] = sum_d s[r][d] * W_sp[f][d] + b_sp[f]
        float* Wt   = lds;               // [128][65] transposed slice of W_sp
        float* srow = lds + 128 * 65;    // [8][256]
        const int row0 = b * 8;
        const int f  = tid & 63;
        const int rh = tid >> 6;         // 0..3 ; handles rows rh and rh+4
        #pragma unroll
        for (int k = 0; k < 8; k++) {
            const int idx = tid + 256 * k;
            const int r = idx >> 8, d = idx & 255;
            srow[r * 256 + d] = s[(row0 + r) * 256 + d];
        }
        float acc0 = b_sp[f];
        float acc1 = acc0;
        for (int pass = 0; pass < 2; pass++) {
            __syncthreads();             // prev-pass Wt reads done (and srow staged)
            #pragma unroll
            for (int k = 0; k < 32; k++) {
                const int idx = tid + 256 * k;
                const int fs = idx >> 7, ds = idx & 127;
                Wt[ds * 65 + fs] = W_sp[fs * 256 + pass * 128 + ds];  // coalesced read
            }
            __syncthreads();
            #pragma unroll 4
            for (int d = 0; d < 128; d++) {
                const float w = Wt[d * 65 + f];
                acc0 += srow[rh * 256 + pass * 128 + d] * w;
                acc1 += srow[(rh + 4) * 256 + pass * 128 + d] * w;
            }
        }
        p_bf[(row0 + rh) * 64 + f]     = __float2bfloat16(acc0);
        p_bf[(row0 + rh + 4) * 64 + f] = __float2bfloat16(acc1);
    } else if (b < 320) {
        // relpos rows r0..r0+3 of the 1023-row delta table
        float* WrT  = lds;               // [64][65] transposed W_rp
        float* femb = lds + 64 * 65;     // [4][64]
        const int r0 = (b - 64) * 4;
        #pragma unroll
        for (int k = 0; k < 16; k++) {
            const int idx = tid + 256 * k;
            const int g = idx >> 6, ff = idx & 63;
            WrT[ff * 65 + g] = W_rp[g * 64 + ff];    // coalesced read
        }
        {
            const int r = tid >> 6, c = tid & 63;
            const float rel = (float)(r0 + r - 511);
            const int K = c & 31;
            const float freq = powf(2056.0f, (2.0f * (float)K) / 64.0f);
            const float ang = rel * PI_F / freq;
            femb[r * 64 + c] = (c < 32) ? sinf(ang) : cosf(ang);
        }
        __syncthreads();
        const int g = tid & 63, r = tid >> 6;
        float acc = b_rp[g];
        #pragma unroll
        for (int ff = 0; ff < 64; ff++) acc += femb[r * 64 + ff] * WrT[ff * 65 + g];
        relT[(r0 + r) * 64 + g] = __float2bfloat16(acc);
    } else {
        // cast W1 (32768 f32) then W2 (16384 f32) -> bf16, float4-vectorized
        #pragma unroll
        for (int k = 0; k < 2; k++) {
            const int idx4 = (b - 320) * 512 + k * 256 + tid;
            const int e = idx4 * 4;
            const float4 v = (e < 32768) ? *(const float4*)&W1[e]
                                         : *(const float4*)&W2[e - 32768];
            __hip_bfloat16* dst = (e < 32768) ? (W1b + e) : (W2b + (e - 32768));
            dst[0] = __float2bfloat16(v.x);
            dst[1] = __float2bfloat16(v.y);
            dst[2] = __float2bfloat16(v.z);
            dst[3] = __float2bfloat16(v.w);
        }
    }
}

// ---------------------------------------------------------------------------
// Main fused kernel. Block = 64 pairs (one i, 64 consecutive j), 256 threads.
// Wave wv computes all 64 rows x output cols [32wv, 32wv+32).
// LDS union (34KB -> 4 blocks/CU): Ash(64x264 bf16) / Hsh(64x136 bf16) /
// Cf(64x132 f32) live in the same bytes, separated by barriers.
// ---------------------------------------------------------------------------
__global__ __launch_bounds__(256, 4) void edge_main(
    const float* __restrict__ t3, const float* __restrict__ sc3,
    const float* __restrict__ pre,
    const float* __restrict__ b1, const float* __restrict__ b2,
    const __hip_bfloat16* __restrict__ p_bf, const __hip_bfloat16* __restrict__ relT,
    const __hip_bfloat16* __restrict__ W1b, const __hip_bfloat16* __restrict__ W2b,
    float* __restrict__ out)
{
    __shared__ char smem[64 * 264 * 2];                    // 33792 B union
    __hip_bfloat16 (*Ash)[264] = (__hip_bfloat16(*)[264])smem;
    __hip_bfloat16 (*Hsh)[136] = (__hip_bfloat16(*)[136])smem;
    float          (*Cf)[132]  = (float(*)[132])smem;

    const int tid = threadIdx.x;
    const int blk = blockIdx.x;
    const int i  = blk >> 3;
    const int j0 = (blk & 7) << 6;

    const int wv   = tid >> 6;
    const int lane = tid & 63;
    const int l16  = lane & 15;
    const int quad = lane >> 4;
    const int nbase = wv * 32;

    // Early issue: biases + kt0 weight fragments (in flight during tile build)
    const float b1v0 = b1[nbase + l16],      b1v1 = b1[nbase + 16 + l16];
    const float b2v0 = b2[nbase + l16],      b2v1 = b2[nbase + 16 + l16];
    const __hip_bfloat16* w1r0 = W1b + (nbase + l16) * 256 + quad * 8;
    const __hip_bfloat16* w1r1 = w1r0 + 16 * 256;
    const __hip_bfloat16* w2r0 = W2b + (nbase + l16) * 128 + quad * 8;
    const __hip_bfloat16* w2r1 = w2r0 + 16 * 128;
    const v8s p10 = *(const v8s*)w1r0;
    const v8s p11 = *(const v8s*)w1r1;
    const v8s p20 = *(const v8s*)w2r0;
    const v8s p21 = *(const v8s*)w2r1;

    // ---- build all_edge tile: A(p_i) B(p_j) C(relpos) D(RBF) E(pre) ----
    #pragma unroll
    for (int c = tid; c < 512; c += 256) {                 // 2 iters
        const int r = c >> 3;
        const int cc = (c & 7) << 3;
        *(uint4*)&Ash[r][cc]       = *(const uint4*)&p_bf[i * 64 + cc];
        *(uint4*)&Ash[r][64 + cc]  = *(const uint4*)&p_bf[(j0 + r) * 64 + cc];
        *(uint4*)&Ash[r][128 + cc] = *(const uint4*)&relT[(i - (j0 + r) + 511) * 64 + cc];
    }
    for (int c = tid; c < 320; c += 256) {                 // pair_repr_pre, 20 f32/row
        const int r = c / 5;
        const int f4 = (c % 5) * 4;
        const float4 v = *(const float4*)&pre[((size_t)i * 512 + j0 + r) * 20 + f4];
        Ash[r][236 + f4 + 0] = __float2bfloat16(v.x);
        Ash[r][236 + f4 + 1] = __float2bfloat16(v.y);
        Ash[r][236 + f4 + 2] = __float2bfloat16(v.z);
        Ash[r][236 + f4 + 3] = __float2bfloat16(v.w);
    }
    {   // RBF: 4 threads/row, 11 features each; distances in-register
        const int r = tid >> 2;
        const int fo = (tid & 3) * 11;
        const int j = j0 + r;
        const float dxt = t3[i * 3 + 0] - t3[j * 3 + 0];
        const float dyt = t3[i * 3 + 1] - t3[j * 3 + 1];
        const float dzt = t3[i * 3 + 2] - t3[j * 3 + 2];
        const float dt = sqrtf(dxt * dxt + dyt * dyt + dzt * dzt);
        const float dxs = sc3[i * 3 + 0] - sc3[j * 3 + 0];
        const float dys = sc3[i * 3 + 1] - sc3[j * 3 + 1];
        const float dzs = sc3[i * 3 + 2] - sc3[j * 3 + 2];
        const float ds = sqrtf(dxs * dxs + dys * dys + dzs * dzs);
        #pragma unroll
        for (int q = 0; q < 11; q++) {
            const int f = fo + q;
            const float d = (f < 22) ? dt : ds;
            const int m = (f < 22) ? f : f - 22;
            const float x = (d - (float)m * (20.0f / 21.0f)) * 1.1f;
            Ash[r][192 + f] = __float2bfloat16(__expf(-x * x));
        }
    }
    __syncthreads();

    // ---- Layer 1: (64x256) @ W1^T -> h slice [*, nbase..nbase+32) ----
    v4f acc[4][2];
    #pragma unroll
    for (int s4 = 0; s4 < 4; s4++)
        #pragma unroll
        for (int n = 0; n < 2; n++) acc[s4][n] = (v4f){0.f, 0.f, 0.f, 0.f};

    #pragma unroll
    for (int kt = 0; kt < 8; kt++) {
        const int ko = kt * 32 + quad * 8;
        const v8s a0 = *(const v8s*)&Ash[ 0 + l16][ko];
        const v8s a1 = *(const v8s*)&Ash[16 + l16][ko];
        const v8s a2 = *(const v8s*)&Ash[32 + l16][ko];
        const v8s a3 = *(const v8s*)&Ash[48 + l16][ko];
        const v8s bb0 = (kt == 0) ? p10 : *(const v8s*)(w1r0 + kt * 32);
        const v8s bb1 = (kt == 0) ? p11 : *(const v8s*)(w1r1 + kt * 32);
        acc[0][0] = __builtin_amdgcn_mfma_f32_16x16x32_bf16(a0, bb0, acc[0][0], 0, 0, 0);
        acc[1][0] = __builtin_amdgcn_mfma_f32_16x16x32_bf16(a1, bb0, acc[1][0], 0, 0, 0);
        acc[2][0] = __builtin_amdgcn_mfma_f32_16x16x32_bf16(a2, bb0, acc[2][0], 0, 0, 0);
        acc[3][0] = __builtin_amdgcn_mfma_f32_16x16x32_bf16(a3, bb0, acc[3][0], 0, 0, 0);
        acc[0][1] = __builtin_amdgcn_mfma_f32_16x16x32_bf16(a0, bb1, acc[0][1], 0, 0, 0);
        acc[1][1] = __builtin_amdgcn_mfma_f32_16x16x32_bf16(a1, bb1, acc[1][1], 0, 0, 0);
        acc[2][1] = __builtin_amdgcn_mfma_f32_16x16x32_bf16(a2, bb1, acc[2][1], 0, 0, 0);
        acc[3][1] = __builtin_amdgcn_mfma_f32_16x16x32_bf16(a3, bb1, acc[3][1], 0, 0, 0);
    }
    __syncthreads();    // all Ash reads done before Hsh overlay write

    #pragma unroll
    for (int s4 = 0; s4 < 4; s4++) {
        #pragma unroll
        for (int n = 0; n < 2; n++) {
            const float bv = n ? b1v1 : b1v0;
            #pragma unroll
            for (int r = 0; r < 4; r++) {
                float v = acc[s4][n][r] + bv;
                v = fmaxf(v, 0.0f);
                Hsh[s4 * 16 + quad * 4 + r][nbase + n * 16 + l16] = __float2bfloat16(v);
            }
        }
    }
    __syncthreads();

    // ---- Layer 2: h(64x128) @ W2^T -> C slice [*, nbase..nbase+32) ----
    v4f acc2[4][2];
    #pragma unroll
    for (int s4 = 0; s4 < 4; s4++)
        #pragma unroll
        for (int n = 0; n < 2; n++) acc2[s4][n] = (v4f){0.f, 0.f, 0.f, 0.f};

    #pragma unroll
    for (int kt = 0; kt < 4; kt++) {
        const int ko = kt * 32 + quad * 8;
        const v8s a0 = *(const v8s*)&Hsh[ 0 + l16][ko];
        const v8s a1 = *(const v8s*)&Hsh[16 + l16][ko];
        const v8s a2 = *(const v8s*)&Hsh[32 + l16][ko];
        const v8s a3 = *(const v8s*)&Hsh[48 + l16][ko];
        const v8s bb0 = (kt == 0) ? p20 : *(const v8s*)(w2r0 + kt * 32);
        const v8s bb1 = (kt == 0) ? p21 : *(const v8s*)(w2r1 + kt * 32);
        acc2[0][0] = __builtin_amdgcn_mfma_f32_16x16x32_bf16(a0, bb0, acc2[0][0], 0, 0, 0);
        acc2[1][0] = __builtin_amdgcn_mfma_f32_16x16x32_bf16(a1, bb0, acc2[1][0], 0, 0, 0);
        acc2[2][0] = __builtin_amdgcn_mfma_f32_16x16x32_bf16(a2, bb0, acc2[2][0], 0, 0, 0);
        acc2[3][0] = __builtin_amdgcn_mfma_f32_16x16x32_bf16(a3, bb0, acc2[3][0], 0, 0, 0);
        acc2[0][1] = __builtin_amdgcn_mfma_f32_16x16x32_bf16(a0, bb1, acc2[0][1], 0, 0, 0);
        acc2[1][1] = __builtin_amdgcn_mfma_f32_16x16x32_bf16(a1, bb1, acc2[1][1], 0, 0, 0);
        acc2[2][1] = __builtin_amdgcn_mfma_f32_16x16x32_bf16(a2, bb1, acc2[2][1], 0, 0, 0);
        acc2[3][1] = __builtin_amdgcn_mfma_f32_16x16x32_bf16(a3, bb1, acc2[3][1], 0, 0, 0);
    }
    __syncthreads();    // all Hsh reads done before Cf overlay write

    // ---- epilogue: +b2, transpose through LDS, float4 coalesced stores ----
    #pragma unroll
    for (int s4 = 0; s4 < 4; s4++) {
        #pragma unroll
        for (int n = 0; n < 2; n++) {
            const float bv = n ? b2v1 : b2v0;
            const int col = nbase + n * 16 + l16;
            #pragma unroll
            for (int r = 0; r < 4; r++) {
                Cf[s4 * 16 + quad * 4 + r][col] = acc2[s4][n][r] + bv;
            }
        }
    }
    __syncthreads();

    const size_t rowbase = (size_t)blk * 64;
    #pragma unroll
    for (int k = 0; k < 8; k++) {                          // 2048 float4 / 256 thr
        const int q = tid + k * 256;
        const int row = q >> 5;
        const int c4 = (q & 31) * 4;
        *(float4*)&out[(rowbase + row) * 128 + c4] = *(const float4*)&Cf[row][c4];
    }
}

// ---------------------------------------------------------------------------
extern "C" void kernel_launch(void* const* d_in, const int* in_sizes, int n_in,
                              void* d_out, int out_size, void* d_ws, size_t ws_size,
                              hipStream_t stream) {
    const float* s    = (const float*)d_in[0];
    const float* t3   = (const float*)d_in[1];
    const float* sc3  = (const float*)d_in[2];
    const float* pre  = (const float*)d_in[3];
    // d_in[4] = p_mask (all-ones, never applied in reference math)
    const float* W_sp = (const float*)d_in[5];
    const float* b_sp = (const float*)d_in[6];
    const float* W_rp = (const float*)d_in[7];
    const float* b_rp = (const float*)d_in[8];
    const float* W1   = (const float*)d_in[9];
    const float* b1   = (const float*)d_in[10];
    const float* W2   = (const float*)d_in[11];
    const float* b2   = (const float*)d_in[12];
    float* out = (float*)d_out;

    char* ws = (char*)d_ws;
    __hip_bfloat16* p_bf = (__hip_bfloat16*)(ws);                          // 64 KiB
    __hip_bfloat16* relT = (__hip_bfloat16*)(ws + 65536);                  // 128 KiB
    __hip_bfloat16* W1b  = (__hip_bfloat16*)(ws + 65536 + 131072);         // 64 KiB
    __hip_bfloat16* W2b  = (__hip_bfloat16*)(ws + 65536 + 131072 + 65536); // 32 KiB

    precompute_kernel<<<344, 256, 0, stream>>>(s, W_sp, b_sp, W_rp, b_rp, W1, W2,
                                               p_bf, relT, W1b, W2b);
    edge_main<<<4096, 256, 0, stream>>>(t3, sc3, pre, b1, b2,
                                        p_bf, relT, W1b, W2b, out);
}